// Round 3
// baseline (1349.994 us; speedup 1.0000x reference)
//
#include <hip/hip_runtime.h>
#include <math.h>

// Problem geometry (B=8, N=4097, D=61, NPOINT=1024, NSAMPLE=16)
#define NB 8
#define NALL 4097
#define NPTS 4096            // N-1 points used for FPS/KNN
#define ND 61
#define NPOINT 1024
#define NS 16
#define XYZ_B_STRIDE 12291   // 4097*3
#define PTS_B_STRIDE 249917  // 4097*61
#define OUTXYZ_B 3075        // 1025*3
#define OUTPTS_B 131200      // 1025*128
#define OUT_PTS_OFF 24600    // 8*1025*3  (out_xyz block precedes out_pts)

// ---------------------------------------------------------------------------
// cls branch: 1 point per batch through 2-layer MLP. Also writes out_xyz[b,0].
// ---------------------------------------------------------------------------
__global__ __launch_bounds__(128)
void cls_kernel(const float* __restrict__ xyz, const float* __restrict__ pts,
                const float* __restrict__ w0, const float* __restrict__ b0,
                const float* __restrict__ g0, const float* __restrict__ bt0,
                const float* __restrict__ m0, const float* __restrict__ v0,
                const float* __restrict__ w1, const float* __restrict__ b1,
                const float* __restrict__ g1, const float* __restrict__ bt1,
                const float* __restrict__ m1, const float* __restrict__ v1,
                float* __restrict__ out)
{
    int b = blockIdx.x, t = threadIdx.x;
    __shared__ float in64[64];
    __shared__ float h[128];
    if (t < 64)
        in64[t] = (t < 3) ? xyz[b * XYZ_B_STRIDE + t]
                          : pts[(size_t)b * PTS_B_STRIDE + (t - 3)];
    __syncthreads();
    float A = g0[t] / sqrtf(v0[t] + 1e-5f);
    float B = (b0[t] - m0[t]) * A + bt0[t];
    float acc = 0.f;
    for (int c = 0; c < 64; ++c) acc = fmaf(w0[t * 64 + c], in64[c], acc);
    h[t] = fmaxf(acc * A + B, 0.f);
    __syncthreads();
    A = g1[t] / sqrtf(v1[t] + 1e-5f);
    B = (b1[t] - m1[t]) * A + bt1[t];
    acc = 0.f;
    for (int c = 0; c < 128; ++c) acc = fmaf(w1[t * 128 + c], h[c], acc);
    out[OUT_PTS_OFF + (size_t)b * OUTPTS_B + t] = fmaxf(acc * A + B, 0.f);
    if (t < 3) out[b * OUTXYZ_B + t] = xyz[b * XYZ_B_STRIDE + t];
}

// ---------------------------------------------------------------------------
// FPS: one block (256 thr = 4 waves) per batch. 1023 serial argmax steps.
// R2 changes vs R1 (VALU-issue surgery; update phase was 57% VALU-busy on
// the 8 active CUs):
//   - float2-paired distance math (SLP -> v_pk_add/mul_f32; per-component
//     rn rounding identical to scalar, still contract-off / bit-exact).
//   - argmax: fmax tree (v_max3-fusable) + equality-mask + v_ffbl instead
//     of the serial 16-deep cmp+cndmask chain.
//   - readlane(63) instead of __shfl (no LDS round-trip); wave slots read
//     as 2x float4; centers as float2+float (2 LDS reads, not 3).
// ---------------------------------------------------------------------------
#define DPP_MAXSTEP(x, ctrl)                                                   \
    x = fmaxf(x, __int_as_float(__builtin_amdgcn_update_dpp(                   \
            0, __float_as_int(x), ctrl, 0xf, 0xf, true)))

__global__ __launch_bounds__(256)
void fps_kernel(const float* __restrict__ xyz, float4* __restrict__ nxyz,
                float* __restrict__ out)
{
#pragma clang fp contract(off)
    int b = blockIdx.x, tid = threadIdx.x;
    __shared__ float2 sxy[NPTS];              // 32 KB
    __shared__ float  szz[NPTS];              // 16 KB
    __shared__ float  cbx[NPOINT], cby[NPOINT], cbz[NPOINT];  // 12 KB
    __shared__ alignas(16) float2 pvpi[2][4];

    float2 px[8], py[8], pz[8], dist[8];
    #pragma unroll
    for (int t = 0; t < 8; ++t) {
        int j = tid * 16 + t * 2;
        const float* p = xyz + b * XYZ_B_STRIDE + 3 + j * 3;  // xyz_r = xyz[:,1:]
        float x0 = p[0], y0 = p[1], z0 = p[2];
        float x1 = p[3], y1 = p[4], z1 = p[5];
        px[t] = make_float2(x0, x1);
        py[t] = make_float2(y0, y1);
        pz[t] = make_float2(z0, z1);
        dist[t] = make_float2(1e10f, 1e10f);
        sxy[j]     = make_float2(x0, y0);
        sxy[j + 1] = make_float2(x1, y1);
        szz[j] = z0; szz[j + 1] = z1;
    }
    __syncthreads();
    float2 c0 = sxy[0];
    float cx = c0.x, cy = c0.y, cz = szz[0];  // far_0 = 0
    if (tid == 0) { cbx[0] = cx; cby[0] = cy; cbz[0] = cz; }

    for (int s = 0; s < NPOINT - 1; ++s) {
        float nd[16];
        #pragma unroll
        for (int t = 0; t < 8; ++t) {
            float dx0 = px[t].x - cx, dx1 = px[t].y - cx;
            float dy0 = py[t].x - cy, dy1 = py[t].y - cy;
            float dz0 = pz[t].x - cz, dz1 = pz[t].y - cz;
            float d0 = (dx0 * dx0 + dy0 * dy0) + dz0 * dz0;
            float d1 = (dx1 * dx1 + dy1 * dy1) + dz1 * dz1;
            float n0 = fminf(dist[t].x, d0);
            float n1 = fminf(dist[t].y, d1);
            dist[t] = make_float2(n0, n1);
            nd[t * 2] = n0; nd[t * 2 + 1] = n1;
        }
        // per-lane max via v_max3-fusable tree (value only; ties resolved below)
        float g0 = fmaxf(fmaxf(nd[0], nd[1]), nd[2]);
        float g1 = fmaxf(fmaxf(nd[3], nd[4]), nd[5]);
        float g2 = fmaxf(fmaxf(nd[6], nd[7]), nd[8]);
        float g3 = fmaxf(fmaxf(nd[9], nd[10]), nd[11]);
        float g4 = fmaxf(fmaxf(nd[12], nd[13]), nd[14]);
        float h0 = fmaxf(fmaxf(g0, g1), g2);
        float h1 = fmaxf(fmaxf(g3, g4), nd[15]);
        float lmax = fmaxf(h0, h1);
        // smallest t achieving lmax (numpy first-max semantics)
        unsigned msk = 0;
        #pragma unroll
        for (int t = 0; t < 16; ++t) msk |= (nd[t] == lmax) ? (1u << t) : 0u;
        int mymi = (tid << 4) + (__ffs(msk) - 1);
        // wave max via DPP chain -> lane 63, then SGPR broadcast
        float red = lmax;
        DPP_MAXSTEP(red, 0x111);   // row_shr:1
        DPP_MAXSTEP(red, 0x112);   // row_shr:2
        DPP_MAXSTEP(red, 0x114);   // row_shr:4
        DPP_MAXSTEP(red, 0x118);   // row_shr:8
        DPP_MAXSTEP(red, 0x142);   // row_bcast:15
        DPP_MAXSTEP(red, 0x143);   // row_bcast:31  -> lane 63 has wave max
        float wmax = __int_as_float(__builtin_amdgcn_readlane(__float_as_int(red), 63));
        // lanes are index-ordered: lowest lane with lmax==wmax holds the
        // smallest qualifying global index
        unsigned long long ball = __ballot(lmax == wmax);
        int first = __ffsll((long long)ball) - 1;
        int bwi = __builtin_amdgcn_readlane(mymi, first);
        int par = s & 1;
        if ((tid & 63) == 0)
            pvpi[par][tid >> 6] = make_float2(wmax, __int_as_float(bwi));
        __syncthreads();
        const float4* pq = (const float4*)&pvpi[par][0];
        float4 qa = pq[0], qb = pq[1];
        float bv = qa.x; int bi = __float_as_int(qa.y);
        if (qa.z > bv) { bv = qa.z; bi = __float_as_int(qa.w); }
        if (qb.x > bv) { bv = qb.x; bi = __float_as_int(qb.y); }
        if (qb.z > bv) { bv = qb.z; bi = __float_as_int(qb.w); }
        float2 cc = sxy[bi];
        cx = cc.x; cy = cc.y; cz = szz[bi];
        if (tid == 0) { cbx[s + 1] = cx; cby[s + 1] = cy; cbz[s + 1] = cz; }
    }
    __syncthreads();
    // single writeout of all centers (+|q|^2 for KNN)
    for (int s = tid; s < NPOINT; s += 256) {
        float x = cbx[s], y = cby[s], z = cbz[s];
        float s2 = (x * x + y * y) + z * z;   // rn, same assoc as reference
        float* o = out + b * OUTXYZ_B + 3 + s * 3;
        o[0] = x; o[1] = y; o[2] = z;
        nxyz[b * NPOINT + s] = make_float4(x, y, z, s2);
    }
}

// ---------------------------------------------------------------------------
// KNN: exact top-16 by (d2, idx). One wave per query row; 4 rows per block.
// d2 computed with the reference's expanded formula in rn arithmetic.
// ---------------------------------------------------------------------------
__global__ __launch_bounds__(256)
void knn_kernel(const float* __restrict__ xyz, const float4* __restrict__ nxyz,
                int* __restrict__ knn)
{
    int bb = blockIdx.x, tid = threadIdx.x;
    int b = bb >> 8;                 // 256 blocks per batch
    int sbase = (bb & 255) * 4;
    __shared__ float sx[NPTS], sy[NPTS], sz[NPTS], sn[NPTS];
    #pragma unroll 1
    for (int t = 0; t < 16; ++t) {
        int j = tid + t * 256;
        const float* p = xyz + b * XYZ_B_STRIDE + 3 + j * 3;
        float x = p[0], y = p[1], z = p[2];
        sx[j] = x; sy[j] = y; sz[j] = z;
        sn[j] = __fadd_rn(__fadd_rn(__fmul_rn(x, x), __fmul_rn(y, y)), __fmul_rn(z, z));
    }
    __syncthreads();
    int wid = tid >> 6, lane = tid & 63;
    int r = b * NPOINT + sbase + wid;
    float4 q = nxyz[r];

    float sv[16]; int si[16];
    #pragma unroll
    for (int k = 0; k < 16; ++k) { sv[k] = 3.0e38f; si[k] = 0x7fffffff; }

    #pragma unroll 1
    for (int t = 0; t < 64; ++t) {
        int j = (t << 6) + lane;
        float dot = __fadd_rn(__fadd_rn(__fmul_rn(q.x, sx[j]), __fmul_rn(q.y, sy[j])),
                              __fmul_rn(q.z, sz[j]));
        float d2 = __fsub_rn(__fadd_rn(q.w, sn[j]), __fmul_rn(2.0f, dot));
        if (d2 < sv[15]) {            // strict <: equal value keeps earlier index
            sv[15] = d2; si[15] = j;
            #pragma unroll
            for (int k = 15; k > 0; --k) {
                if (sv[k] < sv[k - 1]) {
                    float tv = sv[k]; sv[k] = sv[k - 1]; sv[k - 1] = tv;
                    int   ti = si[k]; si[k] = si[k - 1]; si[k - 1] = ti;
                }
            }
        }
    }
    // merge 64 sorted lists: 16 rounds of wave argmin over the heads
    int mykn = 0;
    #pragma unroll 1
    for (int it = 0; it < 16; ++it) {
        float bvv = sv[0]; int bii = si[0];
        #pragma unroll
        for (int off = 32; off; off >>= 1) {
            float ov = __shfl_xor(bvv, off);
            int   oi = __shfl_xor(bii, off);
            if (ov < bvv || (ov == bvv && oi < bii)) { bvv = ov; bii = oi; }
        }
        if (lane == it) mykn = bii;
        bool win = (sv[0] == bvv) && (si[0] == bii);   // idx unique -> one winner
        if (win) {
            #pragma unroll
            for (int k = 0; k < 15; ++k) { sv[k] = sv[k + 1]; si[k] = si[k + 1]; }
            sv[15] = 3.0e38f; si[15] = 0x7fffffff;
        }
    }
    if (lane < 16) knn[r * NS + lane] = mykn;
}

// ---------------------------------------------------------------------------
// Gather + MLP(64->128->128) + maxpool over 16 neighbors. 128 thr = one output
// channel each; W rows held in VGPRs; 8 rows per block amortize the W load.
// ---------------------------------------------------------------------------
__global__ __launch_bounds__(128)
void mlp_kernel(const float* __restrict__ xyz, const float* __restrict__ pts,
                const float4* __restrict__ nxyz, const int* __restrict__ knn,
                const float* __restrict__ w0, const float* __restrict__ b0,
                const float* __restrict__ g0, const float* __restrict__ bt0,
                const float* __restrict__ m0, const float* __restrict__ v0,
                const float* __restrict__ w1, const float* __restrict__ b1,
                const float* __restrict__ g1, const float* __restrict__ bt1,
                const float* __restrict__ m1, const float* __restrict__ v1,
                float* __restrict__ out)
{
    int bb = blockIdx.x, tid = threadIdx.x;
    __shared__ float feat[16 * 64];
    __shared__ float hbuf[16 * 128];
    __shared__ int   kk[16];

    float4 w0r[16], w1r[32];
    const float4* w0p = (const float4*)(w0 + tid * 64);
    #pragma unroll
    for (int i = 0; i < 16; ++i) w0r[i] = w0p[i];
    const float4* w1p = (const float4*)(w1 + tid * 128);
    #pragma unroll
    for (int i = 0; i < 32; ++i) w1r[i] = w1p[i];
    float A0 = g0[tid] / sqrtf(v0[tid] + 1e-5f);
    float B0 = (b0[tid] - m0[tid]) * A0 + bt0[tid];
    float A1 = g1[tid] / sqrtf(v1[tid] + 1e-5f);
    float B1 = (b1[tid] - m1[tid]) * A1 + bt1[tid];

    int r0 = bb * 8;
    int b = r0 >> 10;                 // 8 rows share one batch (8 | 1024)
    for (int qq = 0; qq < 8; ++qq) {
        int r = r0 + qq;
        int s = r & 1023;
        if (tid < 16) kk[tid] = knn[r * NS + tid];
        __syncthreads();
        float4 nq = nxyz[r];
        #pragma unroll
        for (int i = 0; i < 8; ++i) {
            int e = tid + (i << 7);
            int k = e >> 6, c = e & 63;
            int j = kk[k];
            float v;
            if (c < 3) {
                float g = xyz[b * XYZ_B_STRIDE + 3 + j * 3 + c];
                float n = (c == 0) ? nq.x : ((c == 1) ? nq.y : nq.z);
                v = __fsub_rn(g, n);   // g_xyz bit-exact
            } else {
                v = pts[(size_t)b * PTS_B_STRIDE + 61 + (size_t)j * 61 + (c - 3)];
            }
            feat[e] = v;
        }
        __syncthreads();
        #pragma unroll 1
        for (int k = 0; k < 16; ++k) {
            const float4* fv = (const float4*)(feat + (k << 6));
            float acc = 0.f;
            #pragma unroll
            for (int i = 0; i < 16; ++i) {
                float4 f = fv[i];
                acc = fmaf(w0r[i].x, f.x, acc);
                acc = fmaf(w0r[i].y, f.y, acc);
                acc = fmaf(w0r[i].z, f.z, acc);
                acc = fmaf(w0r[i].w, f.w, acc);
            }
            hbuf[(k << 7) + tid] = fmaxf(acc * A0 + B0, 0.f);
        }
        __syncthreads();
        float mx = 0.f;                 // relu outputs >= 0 so 0 is a safe init
        #pragma unroll 1
        for (int k = 0; k < 16; ++k) {
            const float4* hv = (const float4*)(hbuf + (k << 7));
            float acc = 0.f;
            #pragma unroll
            for (int i = 0; i < 32; ++i) {
                float4 f = hv[i];
                acc = fmaf(w1r[i].x, f.x, acc);
                acc = fmaf(w1r[i].y, f.y, acc);
                acc = fmaf(w1r[i].z, f.z, acc);
                acc = fmaf(w1r[i].w, f.w, acc);
            }
            mx = fmaxf(mx, fmaxf(acc * A1 + B1, 0.f));
        }
        out[OUT_PTS_OFF + (size_t)b * OUTPTS_B + (size_t)(1 + s) * 128 + tid] = mx;
        __syncthreads();   // protect kk/feat for next row
    }
}

// ---------------------------------------------------------------------------
extern "C" void kernel_launch(void* const* d_in, const int* in_sizes, int n_in,
                              void* d_out, int out_size, void* d_ws, size_t ws_size,
                              hipStream_t stream) {
    const float* xyz = (const float*)d_in[0];
    const float* pts = (const float*)d_in[1];
    // dict order: sa0 block, cls0 block, sa1 block, cls1 block
    const float* sa_w0 = (const float*)d_in[2];
    const float* sa_b0 = (const float*)d_in[3];
    const float* sa_g0 = (const float*)d_in[4];
    const float* sa_bt0 = (const float*)d_in[5];
    const float* sa_m0 = (const float*)d_in[6];
    const float* sa_v0 = (const float*)d_in[7];
    const float* cls_w0 = (const float*)d_in[8];
    const float* cls_b0 = (const float*)d_in[9];
    const float* cls_g0 = (const float*)d_in[10];
    const float* cls_bt0 = (const float*)d_in[11];
    const float* cls_m0 = (const float*)d_in[12];
    const float* cls_v0 = (const float*)d_in[13];
    const float* sa_w1 = (const float*)d_in[14];
    const float* sa_b1 = (const float*)d_in[15];
    const float* sa_g1 = (const float*)d_in[16];
    const float* sa_bt1 = (const float*)d_in[17];
    const float* sa_m1 = (const float*)d_in[18];
    const float* sa_v1 = (const float*)d_in[19];
    const float* cls_w1 = (const float*)d_in[20];
    const float* cls_b1 = (const float*)d_in[21];
    const float* cls_g1 = (const float*)d_in[22];
    const float* cls_bt1 = (const float*)d_in[23];
    const float* cls_m1 = (const float*)d_in[24];
    const float* cls_v1 = (const float*)d_in[25];

    float* out = (float*)d_out;
    float4* nxyz_ws = (float4*)d_ws;                          // 8192 * 16 B
    int* knn_ws = (int*)((char*)d_ws + NB * NPOINT * sizeof(float4));

    cls_kernel<<<NB, 128, 0, stream>>>(xyz, pts,
        cls_w0, cls_b0, cls_g0, cls_bt0, cls_m0, cls_v0,
        cls_w1, cls_b1, cls_g1, cls_bt1, cls_m1, cls_v1, out);
    fps_kernel<<<NB, 256, 0, stream>>>(xyz, nxyz_ws, out);
    knn_kernel<<<NB * (NPOINT / 4), 256, 0, stream>>>(xyz, nxyz_ws, knn_ws);
    mlp_kernel<<<NB * NPOINT / 8, 128, 0, stream>>>(xyz, pts, nxyz_ws, knn_ws,
        sa_w0, sa_b0, sa_g0, sa_bt0, sa_m0, sa_v0,
        sa_w1, sa_b1, sa_g1, sa_bt1, sa_m1, sa_v1, out);
}